// Round 3
// baseline (1107.489 us; speedup 1.0000x reference)
//
#include <hip/hip_runtime.h>
#include <hip/hip_bf16.h>

#define BB 2
#define TT 2048
#define DMODEL 2048
#define NH 16
#define NKV 4
#define DH 128
#define NV 256
#define TL (TT - NV)   // 1792

typedef __bf16  bf16x8  __attribute__((ext_vector_type(8)));
typedef float   float4v __attribute__((ext_vector_type(4)));
typedef short   short8  __attribute__((ext_vector_type(8)));
typedef short   short4v __attribute__((ext_vector_type(4)));
typedef unsigned short ushort;

__device__ __forceinline__ float bf2f(ushort u) {
    union { float f; unsigned i; } c; c.i = ((unsigned)u) << 16; return c.f;
}
__device__ __forceinline__ ushort f2bf(float f) {
    union { float f; unsigned i; } c; c.f = f;
    unsigned r = c.i + 0x7fff + ((c.i >> 16) & 1);
    return (ushort)(r >> 16);
}

// ---------------------------------------------------------------------------
// GEMM: C[M,N] = A[M,K] @ B[K,N]. A is f32 or bf16 (TA), B is f32,
// C is f32 or bf16 (TC). Internally bf16 MFMA, f32 accumulate.
// 128x128 tile, BK=32, 256 threads.
// MFMA C/D layout: col = lane&15, row = (lane>>4)*4 + reg   [m89/m91]
// A/B frag: elem[j] at [lane&15][(lane>>4)*8 + j]           [m120]
// ---------------------------------------------------------------------------
template<typename TA, typename TC>
__global__ __launch_bounds__(256) void gemm_any(
    const TA* __restrict__ A, const float* __restrict__ Bm,
    TC* __restrict__ C, int M, int N, int K)
{
    __shared__ ushort As[128][40];   // pad 32->40: 80B rows
    __shared__ ushort Bt[128][40];   // B transposed tile: Bt[n][k]

    int tid = threadIdx.x;
    int wave = tid >> 6, lane = tid & 63, quad = lane >> 4, l16 = lane & 15;
    int m0 = blockIdx.y * 128, n0 = blockIdx.x * 128;
    int wr = (wave >> 1) * 64, wc = (wave & 1) * 64;

    float4v acc[4][4];
    for (int i = 0; i < 4; i++)
        for (int j = 0; j < 4; j++)
            acc[i][j] = (float4v){0.f, 0.f, 0.f, 0.f};

    int bn  = tid & 127;         // B-gather column
    int bkc = (tid >> 7) * 16;   // B-gather k-chunk base (0 or 16)

    for (int k0 = 0; k0 < K; k0 += 32) {
        // stage A tile (convert f32->bf16 if needed)
        if constexpr (sizeof(TA) == 4) {
            for (int c = tid; c < 1024; c += 256) {
                int r = c >> 3, col = (c & 7) * 4;
                float4v f = *(const float4v*)&A[(size_t)(m0 + r) * K + k0 + col];
                short4v h;
                h[0] = (short)f2bf(f[0]); h[1] = (short)f2bf(f[1]);
                h[2] = (short)f2bf(f[2]); h[3] = (short)f2bf(f[3]);
                *(short4v*)&As[r][col] = h;
            }
        } else {
            for (int c = tid; c < 512; c += 256) {
                int r = c >> 2, col = (c & 3) * 8;
                *(short8*)&As[r][col] = *(const short8*)&A[(size_t)(m0 + r) * K + k0 + col];
            }
        }
        // stage Bt: strided gather of f32 B, convert to bf16
        {
            const float* bp = &Bm[(size_t)(k0 + bkc) * N + n0 + bn];
            short8 tlo, thi;
            #pragma unroll
            for (int j = 0; j < 8; j++) tlo[j] = (short)f2bf(bp[(size_t)j * N]);
            #pragma unroll
            for (int j = 0; j < 8; j++) thi[j] = (short)f2bf(bp[(size_t)(j + 8) * N]);
            *(short8*)&Bt[bn][bkc]     = tlo;
            *(short8*)&Bt[bn][bkc + 8] = thi;
        }
        __syncthreads();

        bf16x8 af[4], bfr[4];
        #pragma unroll
        for (int i = 0; i < 4; i++) af[i] = *(const bf16x8*)&As[wr + i * 16 + l16][quad * 8];
        #pragma unroll
        for (int j = 0; j < 4; j++) bfr[j] = *(const bf16x8*)&Bt[wc + j * 16 + l16][quad * 8];
        #pragma unroll
        for (int i = 0; i < 4; i++)
            #pragma unroll
            for (int j = 0; j < 4; j++)
                acc[i][j] = __builtin_amdgcn_mfma_f32_16x16x32_bf16(af[i], bfr[j], acc[i][j], 0, 0, 0);
        __syncthreads();
    }

    #pragma unroll
    for (int i = 0; i < 4; i++)
        #pragma unroll
        for (int j = 0; j < 4; j++)
            #pragma unroll
            for (int r = 0; r < 4; r++) {
                int row = m0 + wr + i * 16 + quad * 4 + r;
                int col = n0 + wc + j * 16 + l16;
                if constexpr (sizeof(TC) == 2)
                    C[(size_t)row * N + col] = (TC)f2bf(acc[i][j][r]);
                else
                    C[(size_t)row * N + col] = acc[i][j][r];
            }
}

// ---------------------------------------------------------------------------
// RoPE on Q (bf16, in place), text positions only. cos/sin are f32.
// ---------------------------------------------------------------------------
__global__ __launch_bounds__(256) void rope_q(
    ushort* __restrict__ q, const float* __restrict__ cosp, const float* __restrict__ sinp)
{
    int idx = blockIdx.x * 256 + threadIdx.x;   // over TL*NH*64
    int b = blockIdx.y;
    int i  = idx & 63;
    int h  = (idx >> 6) & 15;
    int tr = idx >> 10;                          // 0..TL-1
    int t  = NV + tr;
    size_t off = ((size_t)(b * TT + t)) * (NH * DH) + h * DH + 2 * i;
    unsigned pk = *(const unsigned*)&q[off];
    float a  = bf2f((ushort)(pk & 0xffff));
    float bb = bf2f((ushort)(pk >> 16));
    float c  = cosp[tr * 64 + i];
    float s  = sinp[tr * 64 + i];
    float ra = a * c - bb * s;
    float rb = a * s + bb * c;
    *(unsigned*)&q[off] = (unsigned)f2bf(ra) | ((unsigned)f2bf(rb) << 16);
}

// ---------------------------------------------------------------------------
// RoPE on K (bf16 in) + write f32 K/V caches in (B,NKV,T,DH) layout (d_out).
// ---------------------------------------------------------------------------
__global__ __launch_bounds__(256) void ropek_cache(
    const ushort* __restrict__ kbuf, const ushort* __restrict__ vbuf,
    const float* __restrict__ cosp, const float* __restrict__ sinp,
    float* __restrict__ kout, float* __restrict__ vout)
{
    int idx = blockIdx.x * 256 + threadIdx.x;   // 2^20
    int i  = idx & 63;
    int kh = (idx >> 6) & 3;
    int t  = (idx >> 8) & 2047;
    int b  = idx >> 19;
    size_t src = ((size_t)(b * TT + t)) * (NKV * DH) + kh * DH + 2 * i;
    size_t dst = ((size_t)((b * NKV + kh) * TT + t)) * DH + 2 * i;
    unsigned pk = *(const unsigned*)&kbuf[src];
    float ka = bf2f((ushort)(pk & 0xffff));
    float kb = bf2f((ushort)(pk >> 16));
    if (t >= NV) {
        int pos = t - NV;
        float c = cosp[pos * 64 + i];
        float s = sinp[pos * 64 + i];
        float ra = ka * c - kb * s;
        float rb = ka * s + kb * c;
        ka = ra; kb = rb;
    }
    kout[dst]     = ka;
    kout[dst + 1] = kb;
    unsigned pv = *(const unsigned*)&vbuf[src];
    vout[dst]     = bf2f((ushort)(pv & 0xffff));
    vout[dst + 1] = bf2f((ushort)(pv >> 16));
}

// ---------------------------------------------------------------------------
// Flash attention. BQ=64, BKEY=64, 4 waves (16 q-rows each), online softmax.
// Q from bf16 qbuf; K/V staged from f32 caches with f32->bf16 convert.
// Output written IN PLACE over qbuf. grid: (T/64, NH, B)
// ---------------------------------------------------------------------------
__global__ __launch_bounds__(256) void attn_kernel(
    ushort* qbuf,
    const float* __restrict__ kcache, const float* __restrict__ vcache)
{
    __shared__ ushort Qs[64][136];
    __shared__ ushort Ks[64][136];
    __shared__ ushort Vt[DH][72];    // V transposed: Vt[d][key]
    __shared__ ushort Ps[64][72];    // P round-trip (C-layout -> A-layout)

    int tid = threadIdx.x;
    int wave = tid >> 6, lane = tid & 63, quad = lane >> 4, l16 = lane & 15;
    int qt = blockIdx.x, h = blockIdx.y, b = blockIdx.z;
    int kh = h >> 2;                 // GQA: N_REP=4
    int q0 = qt * 64;

    // stage Q tile (bf16 direct)
    ushort* qbase = qbuf + ((size_t)(b * TT) + q0) * (NH * DH) + h * DH;
    for (int c = tid; c < 1024; c += 256) {
        int r = c >> 4, col = (c & 15) * 8;
        *(short8*)&Qs[r][col] = *(const short8*)&qbase[(size_t)r * (NH * DH) + col];
    }

    float4v Oacc[8];
    #pragma unroll
    for (int i = 0; i < 8; i++) Oacc[i] = (float4v){0.f, 0.f, 0.f, 0.f};
    float mrow[4], lrow[4];
    #pragma unroll
    for (int i = 0; i < 4; i++) { mrow[i] = -1e30f; lrow[i] = 0.f; }

    int nkt = (q0 < NV) ? (TT / 64) : (qt + 1);   // vision rows attend everything
    const float scale = 0.08838834764831845f;     // 1/sqrt(128)

    const float* kbase = kcache + ((size_t)(b * NKV + kh)) * TT * DH;
    const float* vbase = vcache + ((size_t)(b * NKV + kh)) * TT * DH;

    for (int kt = 0; kt < nkt; kt++) {
        int k0 = kt * 64;
        // stage K tile: f32 -> bf16
        for (int c = tid; c < 2048; c += 256) {
            int r = c >> 5, col = (c & 31) * 4;
            float4v f = *(const float4v*)&kbase[(size_t)(k0 + r) * DH + col];
            short4v hh;
            hh[0] = (short)f2bf(f[0]); hh[1] = (short)f2bf(f[1]);
            hh[2] = (short)f2bf(f[2]); hh[3] = (short)f2bf(f[3]);
            *(short4v*)&Ks[r][col] = hh;
        }
        // stage V transposed: f32 loads, convert, scalar LDS scatter
        {
            int key = tid & 63, dbase = (tid >> 6) * 32;
            const float* vp = &vbase[(size_t)(k0 + key) * DH + dbase];
            #pragma unroll
            for (int j = 0; j < 32; j += 4) {
                float4v f = *(const float4v*)&vp[j];
                Vt[dbase + j + 0][key] = f2bf(f[0]);
                Vt[dbase + j + 1][key] = f2bf(f[1]);
                Vt[dbase + j + 2][key] = f2bf(f[2]);
                Vt[dbase + j + 3][key] = f2bf(f[3]);
            }
        }
        __syncthreads();   // staged tiles (and Qs on first iter) visible

        // S = Q K^T (wave's 16 rows x 64 keys)
        float4v sacc[4];
        #pragma unroll
        for (int t2i = 0; t2i < 4; t2i++) {
            float4v a4 = (float4v){0.f, 0.f, 0.f, 0.f};
            #pragma unroll
            for (int dk = 0; dk < 4; dk++) {
                bf16x8 af = *(const bf16x8*)&Qs[wave * 16 + l16][dk * 32 + quad * 8];
                bf16x8 bf = *(const bf16x8*)&Ks[t2i * 16 + l16][dk * 32 + quad * 8];
                a4 = __builtin_amdgcn_mfma_f32_16x16x32_bf16(af, bf, a4, 0, 0, 0);
            }
            sacc[t2i] = a4;
        }

        // scale + causal mask (diag tile of text rows only)
        bool diag = (q0 >= NV) && (kt == qt);
        #pragma unroll
        for (int t2i = 0; t2i < 4; t2i++)
            #pragma unroll
            for (int i = 0; i < 4; i++) {
                float s = sacc[t2i][i] * scale;
                if (diag) {
                    int qg = q0 + wave * 16 + quad * 4 + i;
                    int kg = k0 + t2i * 16 + l16;
                    if (kg > qg) s = -1e9f;
                }
                sacc[t2i][i] = s;
            }

        // online softmax (row stats replicated across each quad's 16 lanes)
        float alpha[4];
        #pragma unroll
        for (int i = 0; i < 4; i++) {
            float v = fmaxf(fmaxf(sacc[0][i], sacc[1][i]), fmaxf(sacc[2][i], sacc[3][i]));
            #pragma unroll
            for (int off = 1; off < 16; off <<= 1) v = fmaxf(v, __shfl_xor(v, off, 64));
            float mnew = fmaxf(mrow[i], v);
            alpha[i] = __expf(mrow[i] - mnew);
            float ss = 0.f;
            #pragma unroll
            for (int t2i = 0; t2i < 4; t2i++) {
                float p = __expf(sacc[t2i][i] - mnew);
                sacc[t2i][i] = p;
                ss += p;
            }
            #pragma unroll
            for (int off = 1; off < 16; off <<= 1) ss += __shfl_xor(ss, off, 64);
            lrow[i] = lrow[i] * alpha[i] + ss;
            mrow[i] = mnew;
        }
        #pragma unroll
        for (int dt = 0; dt < 8; dt++)
            #pragma unroll
            for (int i = 0; i < 4; i++) Oacc[dt][i] *= alpha[i];

        // P: C-layout -> LDS
        #pragma unroll
        for (int t2i = 0; t2i < 4; t2i++)
            #pragma unroll
            for (int i = 0; i < 4; i++)
                Ps[wave * 16 + quad * 4 + i][t2i * 16 + l16] = f2bf(sacc[t2i][i]);

        __syncthreads();   // Ps write -> read ordering

        // O += P V
        #pragma unroll
        for (int kk = 0; kk < 2; kk++) {
            bf16x8 pf = *(const bf16x8*)&Ps[wave * 16 + l16][kk * 32 + quad * 8];
            #pragma unroll
            for (int dt = 0; dt < 8; dt++) {
                bf16x8 vf = *(const bf16x8*)&Vt[dt * 16 + l16][kk * 32 + quad * 8];
                Oacc[dt] = __builtin_amdgcn_mfma_f32_16x16x32_bf16(pf, vf, Oacc[dt], 0, 0, 0);
            }
        }

        __syncthreads();   // reads drained before next restage
    }

    // epilogue: normalize and store bf16 (in place over qbuf)
    #pragma unroll
    for (int dt = 0; dt < 8; dt++)
        #pragma unroll
        for (int i = 0; i < 4; i++) {
            float o = Oacc[dt][i] / lrow[i];
            qbase[(size_t)(wave * 16 + quad * 4 + i) * (NH * DH) + dt * 16 + l16] = f2bf(o);
        }
}

// ---------------------------------------------------------------------------
extern "C" void kernel_launch(void* const* d_in, const int* in_sizes, int n_in,
                              void* d_out, int out_size, void* d_ws, size_t ws_size,
                              hipStream_t stream) {
    const float* x    = (const float*)d_in[0];
    const float* cosp = (const float*)d_in[1];
    const float* sinp = (const float*)d_in[2];
    const float* wq   = (const float*)d_in[3];
    const float* wk   = (const float*)d_in[4];
    const float* wv   = (const float*)d_in[5];
    const float* wo   = (const float*)d_in[6];

    float* out  = (float*)d_out;                         // (B,T,DMODEL) f32
    float* kout = out + (size_t)BB * TT * DMODEL;        // (B,NKV,T,DH) f32
    float* vout = kout + (size_t)BB * NKV * TT * DH;

    ushort* qbuf = (ushort*)d_ws;                        // (B*T, NH*DH) bf16: 16 MB
    ushort* kbuf = qbuf + (size_t)BB * TT * NH * DH;     // (B*T, NKV*DH) bf16: 4 MB
    ushort* vbuf = kbuf + (size_t)BB * TT * NKV * DH;    // 4 MB

    const int M = BB * TT;  // 4096

    gemm_any<float, ushort><<<dim3((NH * DH) / 128, M / 128), 256, 0, stream>>>(x, wq, qbuf, M, NH * DH, DMODEL);
    gemm_any<float, ushort><<<dim3((NKV * DH) / 128, M / 128), 256, 0, stream>>>(x, wk, kbuf, M, NKV * DH, DMODEL);
    gemm_any<float, ushort><<<dim3((NKV * DH) / 128, M / 128), 256, 0, stream>>>(x, wv, vbuf, M, NKV * DH, DMODEL);

    rope_q<<<dim3(TL * NH * 64 / 256, BB), 256, 0, stream>>>(qbuf, cosp, sinp);
    ropek_cache<<<dim3((BB * TT * NKV * 64) / 256), 256, 0, stream>>>(kbuf, vbuf, cosp, sinp, kout, vout);

    attn_kernel<<<dim3(TT / 64, NH, BB), 256, 0, stream>>>(qbuf, kout, vout);

    gemm_any<ushort, float><<<dim3(DMODEL / 128, M / 128), 256, 0, stream>>>(qbuf, wo, out, M, DMODEL, NH * DH);
}

// Round 4
// 878.360 us; speedup vs baseline: 1.2609x; 1.2609x over previous
//
#include <hip/hip_runtime.h>
#include <hip/hip_bf16.h>

#define BB 2
#define TT 2048
#define DMODEL 2048
#define NH 16
#define NKV 4
#define DH 128
#define NV 256
#define TL (TT - NV)   // 1792

typedef __bf16  bf16x8  __attribute__((ext_vector_type(8)));
typedef float   float4v __attribute__((ext_vector_type(4)));
typedef short   short8  __attribute__((ext_vector_type(8)));
typedef short   short4v __attribute__((ext_vector_type(4)));
typedef unsigned short ushort;

__device__ __forceinline__ float bf2f(ushort u) {
    union { float f; unsigned i; } c; c.i = ((unsigned)u) << 16; return c.f;
}
__device__ __forceinline__ ushort f2bf(float f) {
    union { float f; unsigned i; } c; c.f = f;
    unsigned r = c.i + 0x7fff + ((c.i >> 16) & 1);
    return (ushort)(r >> 16);
}

// ---------------------------------------------------------------------------
// Weight transpose+convert: w[K][N] f32 -> wT[N][K] bf16. 64x64 tiles.
// ---------------------------------------------------------------------------
__global__ __launch_bounds__(256) void wtrans(
    const float* __restrict__ w, ushort* __restrict__ wT, int K, int N)
{
    __shared__ ushort st[64][72];
    int n0 = blockIdx.x * 64, k0 = blockIdx.y * 64;
    int r  = threadIdx.x >> 2;
    int c0 = (threadIdx.x & 3) * 16;
    #pragma unroll
    for (int j = 0; j < 16; j += 4) {
        float4v f = *(const float4v*)&w[(size_t)(k0 + r) * N + n0 + c0 + j];
        st[c0 + j + 0][r] = f2bf(f[0]);
        st[c0 + j + 1][r] = f2bf(f[1]);
        st[c0 + j + 2][r] = f2bf(f[2]);
        st[c0 + j + 3][r] = f2bf(f[3]);
    }
    __syncthreads();
    ushort* dst = &wT[(size_t)(n0 + r) * K + k0];
    *(short8*)&dst[c0]     = *(short8*)&st[r][c0];
    *(short8*)&dst[c0 + 8] = *(short8*)&st[r][c0 + 8];
}

// ---------------------------------------------------------------------------
// V transpose: vbuf[b][t][kh*DH+d] bf16 -> vbfT[(b,kh)][d][t] bf16. 64x64 tiles.
// ---------------------------------------------------------------------------
__global__ __launch_bounds__(256) void vtrans(
    const ushort* __restrict__ vbuf, ushort* __restrict__ vbfT)
{
    __shared__ ushort st[64][72];
    int t0 = blockIdx.x * 64, d0 = blockIdx.y * 64;
    int bk = blockIdx.z;                  // b*NKV + kh
    int b = bk >> 2, kh = bk & 3;
    int r  = threadIdx.x >> 2;
    int c0 = (threadIdx.x & 3) * 16;
    const ushort* src = vbuf + ((size_t)(b * TT + t0 + r)) * (NKV * DH) + kh * DH + d0;
    short8 a0 = *(const short8*)&src[c0];
    short8 a1 = *(const short8*)&src[c0 + 8];
    #pragma unroll
    for (int j = 0; j < 8; j++) {
        st[c0 + j][r]     = (ushort)a0[j];
        st[c0 + 8 + j][r] = (ushort)a1[j];
    }
    __syncthreads();
    ushort* dst = vbfT + ((size_t)(bk * DH + d0 + r)) * TT + t0;
    *(short8*)&dst[c0]     = *(short8*)&st[r][c0];
    *(short8*)&dst[c0 + 8] = *(short8*)&st[r][c0 + 8];
}

// ---------------------------------------------------------------------------
// GEMM: C[M,N] = A[M,K] @ B[K,N] with B supplied TRANSPOSED bf16 (BT[N][K]).
// A f32 (converted on stage) or bf16. 128x128 tile, BK=32, 256 threads.
// ---------------------------------------------------------------------------
template<typename TA, typename TC>
__global__ __launch_bounds__(256) void gemm_bt(
    const TA* __restrict__ A, const ushort* __restrict__ BT,
    TC* __restrict__ C, int M, int N, int K)
{
    __shared__ ushort As[128][40];
    __shared__ ushort Bs[128][40];

    int tid = threadIdx.x;
    int wave = tid >> 6, lane = tid & 63, quad = lane >> 4, l16 = lane & 15;
    int m0 = blockIdx.y * 128, n0 = blockIdx.x * 128;
    int wr = (wave >> 1) * 64, wc = (wave & 1) * 64;

    float4v acc[4][4];
    for (int i = 0; i < 4; i++)
        for (int j = 0; j < 4; j++)
            acc[i][j] = (float4v){0.f, 0.f, 0.f, 0.f};

    for (int k0 = 0; k0 < K; k0 += 32) {
        if constexpr (sizeof(TA) == 4) {
            for (int c = tid; c < 1024; c += 256) {
                int r = c >> 3, col = (c & 7) * 4;
                float4v f = *(const float4v*)&A[(size_t)(m0 + r) * K + k0 + col];
                short4v h;
                h[0] = (short)f2bf(f[0]); h[1] = (short)f2bf(f[1]);
                h[2] = (short)f2bf(f[2]); h[3] = (short)f2bf(f[3]);
                *(short4v*)&As[r][col] = h;
            }
        } else {
            for (int c = tid; c < 512; c += 256) {
                int r = c >> 2, col = (c & 3) * 8;
                *(short8*)&As[r][col] = *(const short8*)&A[(size_t)(m0 + r) * K + k0 + col];
            }
        }
        for (int c = tid; c < 512; c += 256) {
            int r = c >> 2, col = (c & 3) * 8;
            *(short8*)&Bs[r][col] = *(const short8*)&BT[(size_t)(n0 + r) * K + k0 + col];
        }
        __syncthreads();

        bf16x8 af[4], bfr[4];
        #pragma unroll
        for (int i = 0; i < 4; i++) af[i] = *(const bf16x8*)&As[wr + i * 16 + l16][quad * 8];
        #pragma unroll
        for (int j = 0; j < 4; j++) bfr[j] = *(const bf16x8*)&Bs[wc + j * 16 + l16][quad * 8];
        #pragma unroll
        for (int i = 0; i < 4; i++)
            #pragma unroll
            for (int j = 0; j < 4; j++)
                acc[i][j] = __builtin_amdgcn_mfma_f32_16x16x32_bf16(af[i], bfr[j], acc[i][j], 0, 0, 0);
        __syncthreads();
    }

    #pragma unroll
    for (int i = 0; i < 4; i++)
        #pragma unroll
        for (int j = 0; j < 4; j++)
            #pragma unroll
            for (int r = 0; r < 4; r++) {
                int row = m0 + wr + i * 16 + quad * 4 + r;
                int col = n0 + wc + j * 16 + l16;
                if constexpr (sizeof(TC) == 2)
                    C[(size_t)row * N + col] = (TC)f2bf(acc[i][j][r]);
                else
                    C[(size_t)row * N + col] = acc[i][j][r];
            }
}

// ---------------------------------------------------------------------------
// RoPE on Q (bf16, in place), text positions only.
// ---------------------------------------------------------------------------
__global__ __launch_bounds__(256) void rope_q(
    ushort* __restrict__ q, const float* __restrict__ cosp, const float* __restrict__ sinp)
{
    int idx = blockIdx.x * 256 + threadIdx.x;
    int b = blockIdx.y;
    int i  = idx & 63;
    int h  = (idx >> 6) & 15;
    int tr = idx >> 10;
    int t  = NV + tr;
    size_t off = ((size_t)(b * TT + t)) * (NH * DH) + h * DH + 2 * i;
    unsigned pk = *(const unsigned*)&q[off];
    float a  = bf2f((ushort)(pk & 0xffff));
    float bb = bf2f((ushort)(pk >> 16));
    float c  = cosp[tr * 64 + i];
    float s  = sinp[tr * 64 + i];
    *(unsigned*)&q[off] = (unsigned)f2bf(a * c - bb * s) | ((unsigned)f2bf(a * s + bb * c) << 16);
}

// ---------------------------------------------------------------------------
// RoPE K + write f32 K/V caches (d_out) + bf16 K cache (scratch).
// ---------------------------------------------------------------------------
__global__ __launch_bounds__(256) void ropek_cache(
    const ushort* __restrict__ kbuf, const ushort* __restrict__ vbuf,
    const float* __restrict__ cosp, const float* __restrict__ sinp,
    float* __restrict__ kout, float* __restrict__ vout, ushort* __restrict__ kbf)
{
    int idx = blockIdx.x * 256 + threadIdx.x;
    int i  = idx & 63;
    int kh = (idx >> 6) & 3;
    int t  = (idx >> 8) & 2047;
    int b  = idx >> 19;
    size_t src = ((size_t)(b * TT + t)) * (NKV * DH) + kh * DH + 2 * i;
    size_t dst = ((size_t)((b * NKV + kh) * TT + t)) * DH + 2 * i;
    unsigned pk = *(const unsigned*)&kbuf[src];
    float ka = bf2f((ushort)(pk & 0xffff));
    float kb = bf2f((ushort)(pk >> 16));
    if (t >= NV) {
        int pos = t - NV;
        float c = cosp[pos * 64 + i];
        float s = sinp[pos * 64 + i];
        float ra = ka * c - kb * s;
        float rb = ka * s + kb * c;
        ka = ra; kb = rb;
    }
    kout[dst]     = ka;
    kout[dst + 1] = kb;
    *(unsigned*)&kbf[dst] = (unsigned)f2bf(ka) | ((unsigned)f2bf(kb) << 16);
    unsigned pv = *(const unsigned*)&vbuf[src];
    vout[dst]     = bf2f((ushort)(pv & 0xffff));
    vout[dst + 1] = bf2f((ushort)(pv >> 16));
}

// ---------------------------------------------------------------------------
// Flash attention, S^T formulation. BQ=64, BKEY=64, 4 waves.
// S^T = K·Q^T (MFMA A=K, B=Q) -> per-lane scalar softmax state (col = qrow = l16).
// P^T built into PV B-operand via in-register shuffles (no Ps LDS, no barrier).
// O^T = V^T·P^T. Q frags live in registers across the K loop; Qs LDS aliased
// over Ks/Vt -> 35.8 KB LDS -> 4 blocks/CU. 2 barriers/iter.
// grid: (T/64, NH, B)
// ---------------------------------------------------------------------------
__global__ __launch_bounds__(256, 4) void attn_kernel(
    ushort* qbuf,
    const ushort* __restrict__ kbf, const ushort* __restrict__ vbfT)
{
    __shared__ ushort shm[64 * 136 + 128 * 72];   // 35840 B
    ushort (*Qs)[136] = (ushort(*)[136])shm;      // aliased with Ks (Q consumed first)
    ushort (*Ks)[136] = (ushort(*)[136])shm;
    ushort (*Vt)[72]  = (ushort(*)[72])(shm + 64 * 136);

    int tid = threadIdx.x;
    int wave = tid >> 6, lane = tid & 63, quad = lane >> 4, l16 = lane & 15;
    int qt = blockIdx.x, h = blockIdx.y, b = blockIdx.z;
    int kh = h >> 2;
    int q0 = qt * 64;

    // stage Q tile, then hoist this wave's Q fragments into registers
    ushort* qbase = qbuf + ((size_t)(b * TT) + q0) * (NH * DH) + h * DH;
    for (int c = tid; c < 1024; c += 256) {
        int r = c >> 4, col = (c & 15) * 8;
        *(short8*)&Qs[r][col] = *(const short8*)&qbase[(size_t)r * (NH * DH) + col];
    }
    __syncthreads();
    bf16x8 qf[4];
    #pragma unroll
    for (int dk = 0; dk < 4; dk++)
        qf[dk] = *(const bf16x8*)&Qs[wave * 16 + l16][dk * 32 + quad * 8];
    __syncthreads();   // all waves done reading Q before Ks overwrites it

    float4v Oacc[8];
    #pragma unroll
    for (int i = 0; i < 8; i++) Oacc[i] = (float4v){0.f, 0.f, 0.f, 0.f};
    float mrow = -1e30f, lrow = 0.f;

    int nkt = (q0 < NV) ? (TT / 64) : (qt + 1);
    const float scale = 0.08838834764831845f;     // 1/sqrt(128)
    int qg = q0 + wave * 16 + l16;                // this lane's query row

    const ushort* kb2 = kbf  + ((size_t)(b * NKV + kh)) * TT * DH;
    const ushort* vb2 = vbfT + ((size_t)(b * NKV + kh)) * DH * TT;

    int sl0 = ((lane & 16) << 1) + l16;           // ((q&1)*2)*16 + l16
    int sl1 = sl0 + 16;
    bool hi = lane >= 32;                         // q>>1

    for (int kt = 0; kt < nkt; kt++) {
        int k0 = kt * 64;
        // stage K [64][128] bf16 (16 KB, pure b128)
        for (int c = tid; c < 1024; c += 256) {
            int r = c >> 4, col = (c & 15) * 8;
            *(short8*)&Ks[r][col] = *(const short8*)&kb2[(size_t)(k0 + r) * DH + col];
        }
        // stage V^T [128][64] bf16 (16 KB, pure b128; source pre-transposed)
        for (int c = tid; c < 1024; c += 256) {
            int r = c >> 3, col = (c & 7) * 8;
            *(short8*)&Vt[r][col] = *(const short8*)&vb2[(size_t)r * TT + k0 + col];
        }
        __syncthreads();

        // S^T = K·Q^T : lane holds rows key = t2i*16+quad*4+i, col qrow = l16
        float4v sacc[4];
        #pragma unroll
        for (int t2i = 0; t2i < 4; t2i++) {
            float4v a4 = (float4v){0.f, 0.f, 0.f, 0.f};
            #pragma unroll
            for (int dk = 0; dk < 4; dk++) {
                bf16x8 af = *(const bf16x8*)&Ks[t2i * 16 + l16][dk * 32 + quad * 8];
                a4 = __builtin_amdgcn_mfma_f32_16x16x32_bf16(af, qf[dk], a4, 0, 0, 0);
            }
            sacc[t2i] = a4;
        }

        // scale + causal mask (diagonal tile of text rows only)
        bool diag = (q0 >= NV) && (kt == qt);
        #pragma unroll
        for (int t2i = 0; t2i < 4; t2i++)
            #pragma unroll
            for (int i = 0; i < 4; i++) {
                float s = sacc[t2i][i] * scale;
                if (diag && (k0 + t2i * 16 + quad * 4 + i > qg)) s = -1e9f;
                sacc[t2i][i] = s;
            }

        // online softmax: per-lane scalar state, reduce across quads (2 shfls)
        float mx = -1e30f;
        #pragma unroll
        for (int t2i = 0; t2i < 4; t2i++)
            #pragma unroll
            for (int i = 0; i < 4; i++) mx = fmaxf(mx, sacc[t2i][i]);
        mx = fmaxf(mx, __shfl_xor(mx, 16, 64));
        mx = fmaxf(mx, __shfl_xor(mx, 32, 64));
        float mnew = fmaxf(mrow, mx);
        float alpha = __expf(mrow - mnew);
        float ss = 0.f;
        #pragma unroll
        for (int t2i = 0; t2i < 4; t2i++)
            #pragma unroll
            for (int i = 0; i < 4; i++) {
                float p = __expf(sacc[t2i][i] - mnew);
                sacc[t2i][i] = p;
                ss += p;
            }
        ss += __shfl_xor(ss, 16, 64);
        ss += __shfl_xor(ss, 32, 64);
        lrow = lrow * alpha + ss;
        mrow = mnew;
        #pragma unroll
        for (int dt = 0; dt < 8; dt++)
            #pragma unroll
            for (int i = 0; i < 4; i++) Oacc[dt][i] *= alpha;

        // pack P tiles to bf16 dword pairs (per tile: regs 0,1 and 2,3)
        unsigned p01[4], p23[4];
        #pragma unroll
        for (int t2i = 0; t2i < 4; t2i++) {
            p01[t2i] = (unsigned)f2bf(sacc[t2i][0]) | ((unsigned)f2bf(sacc[t2i][1]) << 16);
            p23[t2i] = (unsigned)f2bf(sacc[t2i][2]) | ((unsigned)f2bf(sacc[t2i][3]) << 16);
        }

        // PV: O^T += V^T · P^T, P^T B-operand built by cross-lane shuffles
        #pragma unroll
        for (int kk = 0; kk < 2; kk++) {
            int ta = 2 * kk, tb = 2 * kk + 1;
            unsigned A0 = __shfl(p01[ta], sl0, 64), B0 = __shfl(p01[tb], sl0, 64);
            unsigned A1 = __shfl(p23[ta], sl0, 64), B1 = __shfl(p23[tb], sl0, 64);
            unsigned A2 = __shfl(p01[ta], sl1, 64), B2 = __shfl(p01[tb], sl1, 64);
            unsigned A3 = __shfl(p23[ta], sl1, 64), B3 = __shfl(p23[tb], sl1, 64);
            union { unsigned u[4]; bf16x8 v; } pf;
            pf.u[0] = hi ? B0 : A0;
            pf.u[1] = hi ? B1 : A1;
            pf.u[2] = hi ? B2 : A2;
            pf.u[3] = hi ? B3 : A3;
            #pragma unroll
            for (int dt = 0; dt < 8; dt++) {
                bf16x8 vf = *(const bf16x8*)&Vt[dt * 16 + l16][kk * 32 + quad * 8];
                Oacc[dt] = __builtin_amdgcn_mfma_f32_16x16x32_bf16(vf, pf.v, Oacc[dt], 0, 0, 0);
            }
        }
        __syncthreads();   // reads drained before next restage
    }

    // epilogue: O^T lane holds (d = dt*16+quad*4+i, qrow = wave*16+l16)
    float rinv = 1.f / lrow;
    size_t orow = (size_t)(wave * 16 + l16) * (NH * DH);
    #pragma unroll
    for (int dt = 0; dt < 8; dt++)
        #pragma unroll
        for (int i = 0; i < 4; i += 2) {
            unsigned pk = (unsigned)f2bf(Oacc[dt][i] * rinv)
                        | ((unsigned)f2bf(Oacc[dt][i + 1] * rinv) << 16);
            *(unsigned*)&qbase[orow + dt * 16 + quad * 4 + i] = pk;
        }
}

// ---------------------------------------------------------------------------
extern "C" void kernel_launch(void* const* d_in, const int* in_sizes, int n_in,
                              void* d_out, int out_size, void* d_ws, size_t ws_size,
                              hipStream_t stream) {
    const float* x    = (const float*)d_in[0];
    const float* cosp = (const float*)d_in[1];
    const float* sinp = (const float*)d_in[2];
    const float* wq   = (const float*)d_in[3];
    const float* wk   = (const float*)d_in[4];
    const float* wv   = (const float*)d_in[5];
    const float* wo   = (const float*)d_in[6];

    float* out  = (float*)d_out;                         // (B,T,DMODEL) f32
    float* kout = out + (size_t)BB * TT * DMODEL;        // (B,NKV,T,DH) f32
    float* vout = kout + (size_t)BB * NKV * TT * DH;

    // scratch parked in the `out` region (free until the final GEMM):
    // wqT 4.19M + wkT 1.05M + wvT 1.05M + kbf 2.10M + vbfT 2.10M = 10.49M ushorts
    // (= 21.0 MB) <= out region 16.78M ushorts (33.5 MB).
    ushort* sc   = (ushort*)d_out;
    ushort* wqT  = sc;
    ushort* wkT  = wqT + (size_t)DMODEL * DMODEL;
    ushort* wvT  = wkT + (size_t)(NKV * DH) * DMODEL;
    ushort* kbf  = wvT + (size_t)(NKV * DH) * DMODEL;
    ushort* vbfT = kbf + (size_t)BB * NKV * TT * DH;

    // ws (25.2 MB, proven available): qbuf + kbuf + vbuf; woT aliases kbuf+vbuf
    ushort* qbuf = (ushort*)d_ws;                        // (B*T, NH*DH) bf16
    ushort* kbuf = qbuf + (size_t)BB * TT * NH * DH;
    ushort* vbuf = kbuf + (size_t)BB * TT * NKV * DH;
    ushort* woT  = kbuf;                                 // 4.19M elems = kbuf+vbuf

    const int M = BB * TT;  // 4096

    wtrans<<<dim3(DMODEL / 64, DMODEL / 64), 256, 0, stream>>>(wq, wqT, DMODEL, DMODEL);
    wtrans<<<dim3((NKV * DH) / 64, DMODEL / 64), 256, 0, stream>>>(wk, wkT, DMODEL, NKV * DH);
    wtrans<<<dim3((NKV * DH) / 64, DMODEL / 64), 256, 0, stream>>>(wv, wvT, DMODEL, NKV * DH);

    gemm_bt<float, ushort><<<dim3((NH * DH) / 128, M / 128), 256, 0, stream>>>(x, wqT, qbuf, M, NH * DH, DMODEL);
    gemm_bt<float, ushort><<<dim3((NKV * DH) / 128, M / 128), 256, 0, stream>>>(x, wkT, kbuf, M, NKV * DH, DMODEL);
    gemm_bt<float, ushort><<<dim3((NKV * DH) / 128, M / 128), 256, 0, stream>>>(x, wvT, vbuf, M, NKV * DH, DMODEL);

    rope_q<<<dim3(TL * NH * 64 / 256, BB), 256, 0, stream>>>(qbuf, cosp, sinp);
    ropek_cache<<<dim3((BB * TT * NKV * 64) / 256), 256, 0, stream>>>(kbuf, vbuf, cosp, sinp, kout, vout, kbf);
    vtrans<<<dim3(TT / 64, DH / 64, BB * NKV), 256, 0, stream>>>(vbuf, vbfT);

    // woT overwrites kbuf+vbuf — must follow ropek_cache and vtrans
    wtrans<<<dim3(DMODEL / 64, DMODEL / 64), 256, 0, stream>>>(wo, woT, NH * DH, DMODEL);

    attn_kernel<<<dim3(TT / 64, NH, BB), 256, 0, stream>>>(qbuf, kbf, vbfT);

    gemm_bt<ushort, float><<<dim3(DMODEL / 128, M / 128), 256, 0, stream>>>(qbuf, woT, out, M, DMODEL, NH * DH);
}

// Round 6
// 403.574 us; speedup vs baseline: 2.7442x; 2.1765x over previous
//
#include <hip/hip_runtime.h>
#include <hip/hip_bf16.h>

#define BB 2
#define TT 2048
#define DMODEL 2048
#define NH 16
#define NKV 4
#define DH 128
#define NV 256
#define TL (TT - NV)   // 1792
#define NQKV 3072      // fused projection width: q 2048 | k 512 | v 512

typedef __bf16  bf16x8  __attribute__((ext_vector_type(8)));
typedef float   float4v __attribute__((ext_vector_type(4)));
typedef short   short8  __attribute__((ext_vector_type(8)));
typedef unsigned short ushort;

__device__ __forceinline__ float bf2f(ushort u) {
    union { float f; unsigned i; } c; c.i = ((unsigned)u) << 16; return c.f;
}
__device__ __forceinline__ ushort f2bf(float f) {
    union { float f; unsigned i; } c; c.f = f;
    unsigned r = c.i + 0x7fff + ((c.i >> 16) & 1);
    return (ushort)(r >> 16);
}

// async global->LDS, 16B per lane; LDS dest = wave-uniform base + lane*16
#define GLDS16(g, l) __builtin_amdgcn_global_load_lds( \
    (__attribute__((address_space(1))) void*)(g), \
    (__attribute__((address_space(3))) void*)(l), 16, 0, 0)

// ---------------------------------------------------------------------------
// x f32 -> bf16, 8 elems/thread
// ---------------------------------------------------------------------------
__global__ __launch_bounds__(256) void convert_x(
    const float* __restrict__ x, ushort* __restrict__ xbf)
{
    size_t i = ((size_t)blockIdx.x * 256 + threadIdx.x) * 8;
    float4v f0 = *(const float4v*)&x[i];
    float4v f1 = *(const float4v*)&x[i + 4];
    short8 h;
    h[0] = (short)f2bf(f0[0]); h[1] = (short)f2bf(f0[1]);
    h[2] = (short)f2bf(f0[2]); h[3] = (short)f2bf(f0[3]);
    h[4] = (short)f2bf(f1[0]); h[5] = (short)f2bf(f1[1]);
    h[6] = (short)f2bf(f1[2]); h[7] = (short)f2bf(f1[3]);
    *(short8*)&xbf[i] = h;
}

// ---------------------------------------------------------------------------
// Weight transpose+convert: w[K][N] f32 -> wT[N][K] bf16. 64x64 tiles.
// ---------------------------------------------------------------------------
__global__ __launch_bounds__(256) void wtrans(
    const float* __restrict__ w, ushort* __restrict__ wT, int K, int N)
{
    __shared__ ushort st[64][72];
    int n0 = blockIdx.x * 64, k0 = blockIdx.y * 64;
    int r  = threadIdx.x >> 2;
    int c0 = (threadIdx.x & 3) * 16;
    #pragma unroll
    for (int j = 0; j < 16; j += 4) {
        float4v f = *(const float4v*)&w[(size_t)(k0 + r) * N + n0 + c0 + j];
        st[c0 + j + 0][r] = f2bf(f[0]);
        st[c0 + j + 1][r] = f2bf(f[1]);
        st[c0 + j + 2][r] = f2bf(f[2]);
        st[c0 + j + 3][r] = f2bf(f[3]);
    }
    __syncthreads();
    ushort* dst = &wT[(size_t)(n0 + r) * K + k0];
    *(short8*)&dst[c0]     = *(short8*)&st[r][c0];
    *(short8*)&dst[c0 + 8] = *(short8*)&st[r][c0 + 8];
}

// ---------------------------------------------------------------------------
// wo transpose into the DEAD k/v columns of qkv (chunked layout):
// woT(n,k) -> qkv[(2n + (k>>10))*3072 + 2048 + (k&1023)]
// wo is [K=2048][N=2048] f32. 64x64 tiles; accesses never cross 1024-chunks.
// ---------------------------------------------------------------------------
__global__ __launch_bounds__(256) void wtrans_wo(
    const float* __restrict__ w, ushort* __restrict__ qkv)
{
    __shared__ ushort st[64][72];
    int n0 = blockIdx.x * 64, k0 = blockIdx.y * 64;
    int r  = threadIdx.x >> 2;
    int c0 = (threadIdx.x & 3) * 16;
    #pragma unroll
    for (int j = 0; j < 16; j += 4) {
        float4v f = *(const float4v*)&w[(size_t)(k0 + r) * DMODEL + n0 + c0 + j];
        st[c0 + j + 0][r] = f2bf(f[0]);
        st[c0 + j + 1][r] = f2bf(f[1]);
        st[c0 + j + 2][r] = f2bf(f[2]);
        st[c0 + j + 3][r] = f2bf(f[3]);
    }
    __syncthreads();
    // output row n = n0+r, k-cols k0..k0+63 (within one 1024-chunk)
    ushort* dst = qkv + ((size_t)(2 * (n0 + r) + (k0 >> 10))) * NQKV + 2048 + (k0 & 1023);
    *(short8*)&dst[c0]     = *(short8*)&st[r][c0];
    *(short8*)&dst[c0 + 8] = *(short8*)&st[r][c0 + 8];
}

// ---------------------------------------------------------------------------
// V transpose: qkv v-part [b][t][2560+kh*DH+d] -> vbfT[(b,kh)][d][t]. 64x64.
// ---------------------------------------------------------------------------
__global__ __launch_bounds__(256) void vtrans(
    const ushort* __restrict__ qkv, ushort* __restrict__ vbfT)
{
    __shared__ ushort st[64][72];
    int t0 = blockIdx.x * 64, d0 = blockIdx.y * 64;
    int bk = blockIdx.z;                  // b*NKV + kh
    int b = bk >> 2, kh = bk & 3;
    int r  = threadIdx.x >> 2;
    int c0 = (threadIdx.x & 3) * 16;
    const ushort* src = qkv + ((size_t)(b * TT + t0 + r)) * NQKV + 2560 + kh * DH + d0;
    short8 a0 = *(const short8*)&src[c0];
    short8 a1 = *(const short8*)&src[c0 + 8];
    #pragma unroll
    for (int j = 0; j < 8; j++) {
        st[c0 + j][r]     = (ushort)a0[j];
        st[c0 + 8 + j][r] = (ushort)a1[j];
    }
    __syncthreads();
    ushort* dst = vbfT + ((size_t)(bk * DH + d0 + r)) * TT + t0;
    *(short8*)&dst[c0]     = *(short8*)&st[r][c0];
    *(short8*)&dst[c0 + 8] = *(short8*)&st[r][c0 + 8];
}

// ---------------------------------------------------------------------------
// m97-style GEMM: C[M,N] = A[M,K](bf16, row stride lda) @ BT[N][K](bf16).
// 128x128 tile, BK=32, unpadded 128x32 LDS tiles, global_load_lds 16B staging.
// ---------------------------------------------------------------------------
__global__ __launch_bounds__(256) void gemm_lds(
    const ushort* __restrict__ A, int lda,
    const ushort* __restrict__ BT,
    ushort* __restrict__ C, int ldc, int K)
{
    __shared__ ushort As[128 * 32];
    __shared__ ushort Bs[128 * 32];

    int tid = threadIdx.x;
    int wave = tid >> 6, lane = tid & 63, quad = lane >> 4, l16 = lane & 15;
    int m0 = blockIdx.y * 128, n0 = blockIdx.x * 128;
    int wr = (wave >> 1) * 64, wc = (wave & 1) * 64;

    int srow = tid >> 2, scol = (tid & 3) * 8;
    const ushort* ag = A  + (size_t)(m0 + srow) * lda + scol;
    const ushort* bg = BT + (size_t)(n0 + srow) * K   + scol;
    ushort* la0 = As + (wave * 16) * 32;
    ushort* la1 = As + (64 + wave * 16) * 32;
    ushort* lb0 = Bs + (wave * 16) * 32;
    ushort* lb1 = Bs + (64 + wave * 16) * 32;

    float4v acc[4][4];
    for (int i = 0; i < 4; i++)
        for (int j = 0; j < 4; j++)
            acc[i][j] = (float4v){0.f, 0.f, 0.f, 0.f};

    for (int k0 = 0; k0 < K; k0 += 32) {
        GLDS16(ag + k0,                     la0);
        GLDS16(ag + (size_t)64 * lda + k0,  la1);
        GLDS16(bg + k0,                     lb0);
        GLDS16(bg + (size_t)64 * K + k0,    lb1);
        __syncthreads();

        bf16x8 af[4], bfr[4];
        #pragma unroll
        for (int i = 0; i < 4; i++) af[i] = *(const bf16x8*)&As[(wr + i * 16 + l16) * 32 + quad * 8];
        #pragma unroll
        for (int j = 0; j < 4; j++) bfr[j] = *(const bf16x8*)&Bs[(wc + j * 16 + l16) * 32 + quad * 8];
        #pragma unroll
        for (int i = 0; i < 4; i++)
            #pragma unroll
            for (int j = 0; j < 4; j++)
                acc[i][j] = __builtin_amdgcn_mfma_f32_16x16x32_bf16(af[i], bfr[j], acc[i][j], 0, 0, 0);
        __syncthreads();
    }

    #pragma unroll
    for (int i = 0; i < 4; i++)
        #pragma unroll
        for (int j = 0; j < 4; j++)
            #pragma unroll
            for (int r = 0; r < 4; r++) {
                int row = m0 + wr + i * 16 + quad * 4 + r;
                int col = n0 + wc + j * 16 + l16;
                C[(size_t)row * ldc + col] = f2bf(acc[i][j][r]);
            }
}

// ---------------------------------------------------------------------------
// Final projection GEMM: out[4096][2048] f32 = qkv_q[4096][2048] @ woT,
// where woT is stored CHUNKED in qkv's spare columns (see wtrans_wo).
// B addr for (n, k): Bc + n*6144 + (k>>10)*3072 + (k&1023), Bc = qkv+2048.
// ---------------------------------------------------------------------------
__global__ __launch_bounds__(256) void gemm_out(
    const ushort* __restrict__ A,      // qkv (lda = NQKV, q columns)
    const ushort* __restrict__ Bc,     // qkv + 2048
    float* __restrict__ C)
{
    __shared__ ushort As[128 * 32];
    __shared__ ushort Bs[128 * 32];

    int tid = threadIdx.x;
    int wave = tid >> 6, lane = tid & 63, quad = lane >> 4, l16 = lane & 15;
    int m0 = blockIdx.y * 128, n0 = blockIdx.x * 128;
    int wr = (wave >> 1) * 64, wc = (wave & 1) * 64;

    int srow = tid >> 2, scol = (tid & 3) * 8;
    const ushort* ag = A  + (size_t)(m0 + srow) * NQKV + scol;
    const ushort* bg = Bc + (size_t)(n0 + srow) * 6144 + scol;
    ushort* la0 = As + (wave * 16) * 32;
    ushort* la1 = As + (64 + wave * 16) * 32;
    ushort* lb0 = Bs + (wave * 16) * 32;
    ushort* lb1 = Bs + (64 + wave * 16) * 32;

    float4v acc[4][4];
    for (int i = 0; i < 4; i++)
        for (int j = 0; j < 4; j++)
            acc[i][j] = (float4v){0.f, 0.f, 0.f, 0.f};

    for (int k0 = 0; k0 < 2048; k0 += 32) {
        int koff = ((k0 >> 10) * NQKV) + (k0 & 1023);
        GLDS16(ag + k0,                       la0);
        GLDS16(ag + (size_t)64 * NQKV + k0,   la1);
        GLDS16(bg + koff,                     lb0);
        GLDS16(bg + (size_t)64 * 6144 + koff, lb1);
        __syncthreads();

        bf16x8 af[4], bfr[4];
        #pragma unroll
        for (int i = 0; i < 4; i++) af[i] = *(const bf16x8*)&As[(wr + i * 16 + l16) * 32 + quad * 8];
        #pragma unroll
        for (int j = 0; j < 4; j++) bfr[j] = *(const bf16x8*)&Bs[(wc + j * 16 + l16) * 32 + quad * 8];
        #pragma unroll
        for (int i = 0; i < 4; i++)
            #pragma unroll
            for (int j = 0; j < 4; j++)
                acc[i][j] = __builtin_amdgcn_mfma_f32_16x16x32_bf16(af[i], bfr[j], acc[i][j], 0, 0, 0);
        __syncthreads();
    }

    #pragma unroll
    for (int i = 0; i < 4; i++)
        #pragma unroll
        for (int j = 0; j < 4; j++)
            #pragma unroll
            for (int r = 0; r < 4; r++) {
                int row = m0 + wr + i * 16 + quad * 4 + r;
                int col = n0 + wc + j * 16 + l16;
                C[(size_t)row * DMODEL + col] = acc[i][j][r];
            }
}

// ---------------------------------------------------------------------------
// RoPE on Q (bf16, in place in fused qkv), text positions only.
// ---------------------------------------------------------------------------
__global__ __launch_bounds__(256) void rope_q(
    ushort* __restrict__ qkv, const float* __restrict__ cosp, const float* __restrict__ sinp)
{
    int idx = blockIdx.x * 256 + threadIdx.x;
    int b = blockIdx.y;
    int i  = idx & 63;
    int h  = (idx >> 6) & 15;
    int tr = idx >> 10;
    int t  = NV + tr;
    size_t off = ((size_t)(b * TT + t)) * NQKV + h * DH + 2 * i;
    unsigned pk = *(const unsigned*)&qkv[off];
    float a  = bf2f((ushort)(pk & 0xffff));
    float bb = bf2f((ushort)(pk >> 16));
    float c  = cosp[tr * 64 + i];
    float s  = sinp[tr * 64 + i];
    *(unsigned*)&qkv[off] = (unsigned)f2bf(a * c - bb * s) | ((unsigned)f2bf(a * s + bb * c) << 16);
}

// ---------------------------------------------------------------------------
// RoPE K + write f32 K/V caches (d_out) + bf16 K cache (scratch).
// ---------------------------------------------------------------------------
__global__ __launch_bounds__(256) void ropek_cache(
    const ushort* __restrict__ qkv,
    const float* __restrict__ cosp, const float* __restrict__ sinp,
    float* __restrict__ kout, float* __restrict__ vout, ushort* __restrict__ kbf)
{
    int idx = blockIdx.x * 256 + threadIdx.x;
    int i  = idx & 63;
    int kh = (idx >> 6) & 3;
    int t  = (idx >> 8) & 2047;
    int b  = idx >> 19;
    size_t row = ((size_t)(b * TT + t)) * NQKV;
    size_t dst = ((size_t)((b * NKV + kh) * TT + t)) * DH + 2 * i;
    unsigned pk = *(const unsigned*)&qkv[row + 2048 + kh * DH + 2 * i];
    float ka = bf2f((ushort)(pk & 0xffff));
    float kb = bf2f((ushort)(pk >> 16));
    if (t >= NV) {
        int pos = t - NV;
        float c = cosp[pos * 64 + i];
        float s = sinp[pos * 64 + i];
        float ra = ka * c - kb * s;
        float rb = ka * s + kb * c;
        ka = ra; kb = rb;
    }
    kout[dst]     = ka;
    kout[dst + 1] = kb;
    *(unsigned*)&kbf[dst] = (unsigned)f2bf(ka) | ((unsigned)f2bf(kb) << 16);
    unsigned pv = *(const unsigned*)&qkv[row + 2560 + kh * DH + 2 * i];
    vout[dst]     = bf2f((ushort)(pv & 0xffff));
    vout[dst + 1] = bf2f((ushort)(pv >> 16));
}

// ---------------------------------------------------------------------------
// Flash attention, S^T formulation with global_load_lds staging into chunked
// LDS (32-elem columns, 64B rows). LDS 32 KB. grid: (T/64, NH, B)
// ---------------------------------------------------------------------------
__global__ __launch_bounds__(256, 4) void attn_kernel(
    ushort* qkv,
    const ushort* __restrict__ kbf, const ushort* __restrict__ vbfT)
{
    __shared__ ushort shm[16384];         // 32 KB
    ushort* Kc = shm;                     // [4 chunks][64 rows][32] (Q aliased here)
    ushort* Vc = shm + 8192;              // [2 chunks][128 rows][32]

    int tid = threadIdx.x;
    int wave = tid >> 6, lane = tid & 63, quad = lane >> 4, l16 = lane & 15;
    int qt = blockIdx.x, h = blockIdx.y, b = blockIdx.z;
    int kh = h >> 2;
    int q0 = qt * 64;

    int srow = tid >> 2, scol = (tid & 3) * 8;   // staging coords

    // stage Q tile into Kc (aliased), hoist fragments, release
    ushort* qbase = qkv + ((size_t)(b * TT) + q0) * NQKV + h * DH;
    #pragma unroll
    for (int dk = 0; dk < 4; dk++)
        GLDS16(qbase + (size_t)srow * NQKV + dk * 32 + scol, Kc + dk * 2048 + wave * 512);
    __syncthreads();
    bf16x8 qf[4];
    #pragma unroll
    for (int dk = 0; dk < 4; dk++)
        qf[dk] = *(const bf16x8*)&Kc[dk * 2048 + (wave * 16 + l16) * 32 + quad * 8];
    __syncthreads();   // all waves done reading Q before K staging overwrites

    float4v Oacc[8];
    #pragma unroll
    for (int i = 0; i < 8; i++) Oacc[i] = (float4v){0.f, 0.f, 0.f, 0.f};
    float mrow = -1e30f, lrow = 0.f;

    int nkt = (q0 < NV) ? (TT / 64) : (qt + 1);
    const float scale = 0.08838834764831845f;     // 1/sqrt(128)
    int qg = q0 + wave * 16 + l16;                // this lane's query row

    const ushort* kb2 = kbf  + ((size_t)(b * NKV + kh)) * TT * DH;
    const ushort* vb2 = vbfT + ((size_t)(b * NKV + kh)) * DH * TT;

    int sl0 = ((lane & 16) << 1) + l16;
    int sl1 = sl0 + 16;
    bool hi = lane >= 32;

    for (int kt = 0; kt < nkt; kt++) {
        int k0 = kt * 64;
        #pragma unroll
        for (int dk = 0; dk < 4; dk++)
            GLDS16(kb2 + (size_t)(k0 + srow) * DH + dk * 32 + scol, Kc + dk * 2048 + wave * 512);
        #pragma unroll
        for (int kk = 0; kk < 2; kk++)
            #pragma unroll
            for (int p = 0; p < 2; p++)
                GLDS16(vb2 + (size_t)(p * 64 + srow) * TT + k0 + kk * 32 + scol,
                       Vc + kk * 4096 + (p * 64 + wave * 16) * 32);
        __syncthreads();

        // S^T = K·Q^T : lane holds key rows t2i*16+quad*4+i, q-col l16
        float4v sacc[4];
        #pragma unroll
        for (int t2i = 0; t2i < 4; t2i++) {
            float4v a4 = (float4v){0.f, 0.f, 0.f, 0.f};
            #pragma unroll
            for (int dk = 0; dk < 4; dk++) {
                bf16x8 af = *(const bf16x8*)&Kc[dk * 2048 + (t2i * 16 + l16) * 32 + quad * 8];
                a4 = __builtin_amdgcn_mfma_f32_16x16x32_bf16(af, qf[dk], a4, 0, 0, 0);
            }
            sacc[t2i] = a4;
        }

        bool diag = (q0 >= NV) && (kt == qt);
        #pragma unroll
        for (int t2i = 0; t2i < 4; t2i++)
            #pragma unroll
            for (int i = 0; i < 4; i++) {
                float s = sacc[t2i][i] * scale;
                if (diag && (k0 + t2i * 16 + quad * 4 + i > qg)) s = -1e9f;
                sacc[t2i][i] = s;
            }

        float mx = -1e30f;
        #pragma unroll
        for (int t2i = 0; t2i < 4; t2i++)
            #pragma unroll
            for (int i = 0; i < 4; i++) mx = fmaxf(mx, sacc[t2i][i]);
        mx = fmaxf(mx, __shfl_xor(mx, 16, 64));
        mx = fmaxf(mx, __shfl_xor(mx, 32, 64));
        float mnew = fmaxf(mrow, mx);
        float alpha = __expf(mrow - mnew);
        float ss = 0.f;
        #pragma unroll
        for (int t2i = 0; t2i < 4; t2i++)
            #pragma unroll
            for (int i = 0; i < 4; i++) {
                float p = __expf(sacc[t2i][i] - mnew);
                sacc[t2i][i] = p;
                ss += p;
            }
        ss += __shfl_xor(ss, 16, 64);
        ss += __shfl_xor(ss, 32, 64);
        lrow = lrow * alpha + ss;
        mrow = mnew;
        #pragma unroll
        for (int dt = 0; dt < 8; dt++)
            #pragma unroll
            for (int i = 0; i < 4; i++) Oacc[dt][i] *= alpha;

        unsigned p01[4], p23[4];
        #pragma unroll
        for (int t2i = 0; t2i < 4; t2i++) {
            p01[t2i] = (unsigned)f2bf(sacc[t2i][0]) | ((unsigned)f2bf(sacc[t2i][1]) << 16);
            p23[t2i] = (unsigned)f2bf(sacc[t2i][2]) | ((unsigned)f2bf(sacc[t2i][3]) << 16);
        }

        #pragma unroll
        for (int kk = 0; kk < 2; kk++) {
            int ta = 2 * kk, tb = 2 * kk + 1;
            unsigned A0 = __shfl(p01[ta], sl0, 64), B0 = __shfl(p01[tb], sl0, 64);
            unsigned A1 = __shfl(p23[ta], sl0, 64), B1 = __shfl(p23[tb], sl0, 64);
            unsigned A2 = __shfl(p01[ta], sl1, 64), B2 = __shfl(p01[tb], sl1, 64);
            unsigned A3 = __shfl(p23[ta], sl1, 64), B3 = __shfl(p23[tb], sl1, 64);
            union { unsigned u[4]; bf16x8 v; } pf;
            pf.u[0] = hi ? B0 : A0;
            pf.u[1] = hi ? B1 : A1;
            pf.u[2] = hi ? B2 : A2;
            pf.u[3] = hi ? B3 : A3;
            #pragma unroll
            for (int dt = 0; dt < 8; dt++) {
                bf16x8 vf = *(const bf16x8*)&Vc[kk * 4096 + (dt * 16 + l16) * 32 + quad * 8];
                Oacc[dt] = __builtin_amdgcn_mfma_f32_16x16x32_bf16(vf, pf.v, Oacc[dt], 0, 0, 0);
            }
        }
        __syncthreads();   // reads drained before next restage
    }

    // epilogue: O^T lane holds (d = dt*16+quad*4+i, qrow = wave*16+l16)
    float rinv = 1.f / lrow;
    size_t orow = (size_t)(wave * 16 + l16) * NQKV;
    #pragma unroll
    for (int dt = 0; dt < 8; dt++)
        #pragma unroll
        for (int i = 0; i < 4; i += 2) {
            unsigned pk = (unsigned)f2bf(Oacc[dt][i] * rinv)
                        | ((unsigned)f2bf(Oacc[dt][i + 1] * rinv) << 16);
            *(unsigned*)&qbase[orow + dt * 16 + quad * 4 + i] = pk;
        }
}

// ---------------------------------------------------------------------------
extern "C" void kernel_launch(void* const* d_in, const int* in_sizes, int n_in,
                              void* d_out, int out_size, void* d_ws, size_t ws_size,
                              hipStream_t stream) {
    const float* x    = (const float*)d_in[0];
    const float* cosp = (const float*)d_in[1];
    const float* sinp = (const float*)d_in[2];
    const float* wq   = (const float*)d_in[3];
    const float* wk   = (const float*)d_in[4];
    const float* wv   = (const float*)d_in[5];
    const float* wo   = (const float*)d_in[6];

    float* out  = (float*)d_out;                         // (B,T,DMODEL) f32
    float* kout = out + (size_t)BB * TT * DMODEL;        // (B,NKV,T,DH) f32
    float* vout = kout + (size_t)BB * NKV * TT * DH;

    // scratch in the out region (16.78M ushorts), all DEAD before the final
    // GEMM writes out (gemm_out reads only qkv in ws):
    //   wqkvT [0, 6.29M)        — dead after QKV GEMM
    //   xbf   [6.29M, 14.68M)   — dead after QKV GEMM
    //   kbf   [6.29M, 8.39M)    — dead after attn
    //   vbfT  [8.39M, 10.49M)   — dead after attn
    ushort* sc    = (ushort*)d_out;
    ushort* wqkvT = sc;                                   // [3072][2048] bf16
    ushort* xbf   = sc + (size_t)NQKV * DMODEL;           // [4096][2048] bf16
    ushort* kbf   = sc + (size_t)NQKV * DMODEL;           // (B,NKV,T,DH) bf16
    ushort* vbfT  = kbf + (size_t)BB * NKV * TT * DH;     // (B,NKV,DH,T) bf16

    // ws: fused qkv buffer (B*T, 3072) bf16 = 25.2 MB. After ropek/vtrans
    // consume the k/v columns, woT is stored chunked in those spare columns.
    ushort* qkv = (ushort*)d_ws;

    const int M = BB * TT;  // 4096

    convert_x<<<dim3((size_t)M * DMODEL / 2048), 256, 0, stream>>>(x, xbf);
    wtrans<<<dim3(DMODEL / 64, DMODEL / 64), 256, 0, stream>>>(wq, wqkvT, DMODEL, DMODEL);
    wtrans<<<dim3((NKV * DH) / 64, DMODEL / 64), 256, 0, stream>>>(wk, wqkvT + (size_t)2048 * DMODEL, DMODEL, NKV * DH);
    wtrans<<<dim3((NKV * DH) / 64, DMODEL / 64), 256, 0, stream>>>(wv, wqkvT + (size_t)2560 * DMODEL, DMODEL, NKV * DH);

    // fused QKV projection: [4096,2048] @ [2048,3072] -> qkv [4096][3072]
    gemm_lds<<<dim3(NQKV / 128, M / 128), 256, 0, stream>>>(
        xbf, DMODEL, wqkvT, qkv, NQKV, DMODEL);

    rope_q<<<dim3(TL * NH * 64 / 256, BB), 256, 0, stream>>>(qkv, cosp, sinp);
    ropek_cache<<<dim3((BB * TT * NKV * 64) / 256), 256, 0, stream>>>(qkv, cosp, sinp, kout, vout, kbf);
    vtrans<<<dim3(TT / 64, DH / 64, BB * NKV), 256, 0, stream>>>(qkv, vbfT);

    // wo -> chunked woT in qkv spare cols; AFTER ropek_cache+vtrans (they read
    // the k/v columns this overwrites)
    wtrans_wo<<<dim3(DMODEL / 64, DMODEL / 64), 256, 0, stream>>>(wo, qkv);

    attn_kernel<<<dim3(TT / 64, NH, BB), 256, 0, stream>>>(qkv, kbf, vbfT);

    // output projection: qkv q-cols @ chunked-woT -> out f32 (d_out scratch dead)
    gemm_out<<<dim3(DMODEL / 128, M / 128), 256, 0, stream>>>(qkv, qkv + 2048, out);
}